// Round 4
// baseline (152.298 us; speedup 1.0000x reference)
//
#include <hip/hip_runtime.h>
#include <math.h>

#define B_ 8
#define N_ 2048
#define C_ 512
#define G_ 32          // chunks per batch
#define L_ 64          // chunk length = N_/G_

// ---- workspace layout (in floats) ----
static const size_t OFF_V1   = 0;                    // 512
static const size_t OFF_V2   = OFF_V1 + 512;         // 512
static const size_t OFF_S1   = OFF_V2 + 512;         // 16384
static const size_t OFF_S2   = OFF_S1 + 16384;       // 16384
static const size_t OFF_Z    = OFF_S2 + 16384;       // 16384 sorted s2
static const size_t OFF_IDX  = OFF_Z + 16384;        // 16384 perm (int)
static const size_t OFF_P    = OFF_IDX + 16384;      // 16384 p = exp(z-m2)
static const size_t OFF_Q    = OFF_P + 16384;        // 16384 q = exp(0.2(z-m2))
static const size_t OFF_CHP  = OFF_Q + 16384;        // 131072 chunk P sums -> suffix offsets
static const size_t OFF_CHQ  = OFF_CHP + 131072;     // 131072 chunk Q sums -> suffix offsets
static const size_t OFF_TOTQ = OFF_CHQ + 131072;     // 4096 per-(b,c) total Q
static const size_t OFF_FP   = OFF_TOTQ + 4096;      // 16384 per-row fP = wP/den
static const size_t OFF_FQ   = OFF_FP + 16384;       // 16384 per-row fQ = wQ/den
static const size_t OFF_ROWS = OFF_FQ + 16384;       // 16384 rows sorted by split (int)
static const size_t OFF_POS  = OFF_ROWS + 16384;     // 8*2050 bucket starts (int)
// total ~= 0.42M floats ~= 1.7 MB

// K1: v1 = w @ a1, v2 = w @ a2
__global__ __launch_bounds__(64) void k_wa(const float* __restrict__ w,
                                           const float* __restrict__ a,
                                           float* __restrict__ v1, float* __restrict__ v2) {
    int k = blockIdx.x, lane = threadIdx.x;
    float acc1 = 0.f, acc2 = 0.f;
    for (int c = lane; c < C_; c += 64) {
        float wv = w[k * C_ + c];
        acc1 += wv * a[c];
        acc2 += wv * a[C_ + c];
    }
    for (int o = 32; o > 0; o >>= 1) { acc1 += __shfl_down(acc1, o); acc2 += __shfl_down(acc2, o); }
    if (lane == 0) { v1[k] = acc1; v2[k] = acc2; }
}

// K2: s1[r] = x[r,:]·v1, s2[r] = x[r,:]·v2
__global__ __launch_bounds__(256) void k_s(const float* __restrict__ x,
                                           const float* __restrict__ v1,
                                           const float* __restrict__ v2,
                                           float* __restrict__ s1, float* __restrict__ s2) {
    __shared__ __align__(16) float sv1[C_];
    __shared__ __align__(16) float sv2[C_];
    int tid = threadIdx.x;
    for (int c = tid; c < C_; c += 256) { sv1[c] = v1[c]; sv2[c] = v2[c]; }
    __syncthreads();
    int wave = tid >> 6, lane = tid & 63;
    int r = blockIdx.x * 4 + wave;
    const float4* xr  = reinterpret_cast<const float4*>(x + (size_t)r * C_);
    const float4* w1p = reinterpret_cast<const float4*>(sv1);
    const float4* w2p = reinterpret_cast<const float4*>(sv2);
    float a1 = 0.f, a2 = 0.f;
    for (int half = 0; half < 2; ++half) {
        int c4 = lane + half * 64;
        float4 xv = xr[c4], w1 = w1p[c4], w2 = w2p[c4];
        a1 += xv.x*w1.x + xv.y*w1.y + xv.z*w1.z + xv.w*w1.w;
        a2 += xv.x*w2.x + xv.y*w2.y + xv.z*w2.z + xv.w*w2.w;
    }
    for (int o = 32; o > 0; o >>= 1) { a1 += __shfl_down(a1, o); a2 += __shfl_down(a2, o); }
    if (lane == 0) { s1[r] = a1; s2[r] = a2; }
}

// K3: rank-by-counting sort of s2 -> z (sorted), idx (perm), p, q
__global__ __launch_bounds__(256) void k_rank(const float* __restrict__ s2,
                                              float* __restrict__ z, int* __restrict__ idxArr,
                                              float* __restrict__ pArr, float* __restrict__ qArr) {
    __shared__ float sval[N_];
    __shared__ float sred[256];
    __shared__ int   srnk[256];
    int blk = blockIdx.x;
    int b = blk >> 5, grp = blk & 31;
    int tid = threadIdx.x;
    int le = tid & 63, qtr = tid >> 6;
    for (int i = tid; i < N_; i += 256) sval[i] = s2[(size_t)b * N_ + i];
    __syncthreads();
    int e = grp * 64 + le;
    float val = sval[e];
    int base = qtr * 512;
    int rank = 0;
    float mx = -3.4e38f;
    #pragma unroll 8
    for (int i = 0; i < 512; ++i) {
        int t = base + i;
        float v = sval[t];
        mx = fmaxf(mx, v);
        rank += (v < val) || (v == val && t < e);
    }
    srnk[tid] = rank;
    sred[tid] = mx;
    __syncthreads();
    for (int o = 128; o > 0; o >>= 1) {
        if (tid < o) sred[tid] = fmaxf(sred[tid], sred[tid + o]);
        __syncthreads();
    }
    float m2 = sred[0];
    if (qtr == 0) {
        int rk = srnk[le] + srnk[le + 64] + srnk[le + 128] + srnk[le + 192];
        float d = val - m2;
        size_t pos = (size_t)b * N_ + rk;
        z[pos]      = val;
        idxArr[pos] = e;
        pArr[pos]   = __expf(d);
        qArr[pos]   = __expf(0.2f * d);
    }
}

// K4: per-chunk vector sums chP/chQ[b,g,c]
__global__ __launch_bounds__(512) void k_chunk(const float* __restrict__ x,
                                               const int* __restrict__ idxArr,
                                               const float* __restrict__ pArr,
                                               const float* __restrict__ qArr,
                                               float* __restrict__ chP, float* __restrict__ chQ) {
    int bg = blockIdx.x, b = bg >> 5, g = bg & 31;
    int c = threadIdx.x;
    __shared__ int   srow[L_];
    __shared__ float spv[L_], sqv[L_];
    if (c < L_) {
        int j = g * L_ + c;
        srow[c] = idxArr[b * N_ + j];
        spv[c]  = pArr[b * N_ + j];
        sqv[c]  = qArr[b * N_ + j];
    }
    __syncthreads();
    const float* xb = x + (size_t)b * N_ * C_;
    float accP = 0.f, accQ = 0.f;
    for (int t = 0; t < L_; ++t) {
        float xv = xb[(size_t)srow[t] * C_ + c];
        accP += spv[t] * xv;
        accQ += sqv[t] * xv;
    }
    chP[(size_t)bg * C_ + c] = accP;
    chQ[(size_t)bg * C_ + c] = accQ;
}

// K5: per-batch prep (one block per batch, 1024 threads):
//  A) scalar exclusive prefixes of p,q (LDS only)
//  B) chunk sums -> exclusive suffix offsets in place + totQ
//  C) per output row: binary search split k, factors fP/fQ, bucket count
//  D) scan bucket counts -> posStart
//  E) scatter rows sorted by bucket
__global__ __launch_bounds__(1024) void k_prep(const float* __restrict__ s1,
                                               const float* __restrict__ z,
                                               const float* __restrict__ pArr,
                                               const float* __restrict__ qArr,
                                               float* __restrict__ chP,
                                               float* __restrict__ chQ,
                                               float* __restrict__ totQ,
                                               float* __restrict__ fPArr,
                                               float* __restrict__ fQArr,
                                               int* __restrict__ rowsSorted,
                                               int* __restrict__ posStart) {
    __shared__ float Ppre[2049], Qpre[2049];
    __shared__ float zv[N_];
    __shared__ int   cnt[2049];
    __shared__ int   ps[2050];
    __shared__ float wsP[16], wsQ[16], woP[16], woQ[16];
    __shared__ int   wsC[16], woC[16];
    int b = blockIdx.x, tid = threadIdx.x, lane = tid & 63, wid = tid >> 6;
    size_t ib = (size_t)b * N_;

    for (int i = tid; i < 2049; i += 1024) cnt[i] = 0;
    zv[2*tid]   = z[ib + 2*tid];
    zv[2*tid+1] = z[ib + 2*tid+1];

    // --- A: scalar scans of p and q ---
    float p0 = pArr[ib + 2*tid], p1 = pArr[ib + 2*tid+1];
    float q0 = qArr[ib + 2*tid], q1 = qArr[ib + 2*tid+1];
    float pv = p0 + p1, qv = q0 + q1;
    float pi = pv, qi = qv;
    for (int o = 1; o < 64; o <<= 1) {
        float tp = __shfl_up(pi, o), tq2 = __shfl_up(qi, o);
        if (lane >= o) { pi += tp; qi += tq2; }
    }
    if (lane == 63) { wsP[wid] = pi; wsQ[wid] = qi; }
    __syncthreads();
    if (wid == 0 && lane < 16) {
        float sp = wsP[lane], sq = wsQ[lane];
        float ip = sp, iq = sq;
        for (int o = 1; o < 16; o <<= 1) {
            float tp = __shfl_up(ip, o), tq2 = __shfl_up(iq, o);
            if (lane >= o) { ip += tp; iq += tq2; }
        }
        woP[lane] = ip - sp; woQ[lane] = iq - sq;
    }
    // --- B: chunk suffix offsets (independent of A's tail) ---
    {
        int c = tid & 511, sel = tid >> 9;
        float* arr = sel ? chQ : chP;
        float v[G_];
        #pragma unroll
        for (int g = 0; g < G_; ++g)
            v[g] = arr[((size_t)(b * G_ + g)) * C_ + c];
        float run = 0.f;
        #pragma unroll
        for (int g = G_ - 1; g >= 0; --g) {
            float t = v[g];
            arr[((size_t)(b * G_ + g)) * C_ + c] = run;
            run += t;
        }
        if (sel) totQ[b * C_ + c] = run;
    }
    __syncthreads();
    float inclP = pi + woP[wid], inclQ = qi + woQ[wid];
    float exclP = inclP - pv,    exclQ = inclQ - qv;
    Ppre[2*tid]   = exclP;  Ppre[2*tid+1] = exclP + p0;
    Qpre[2*tid]   = exclQ;  Qpre[2*tid+1] = exclQ + q0;
    if (tid == 1023) { Ppre[2048] = inclP; Qpre[2048] = inclQ; }
    __syncthreads();

    // --- C: per-row split + factors + bucket count ---
    float m2   = zv[N_ - 1];
    float Ptot = Ppre[2048];
    int kk[2], sl[2];
    #pragma unroll
    for (int h = 0; h < 2; ++h) {
        int rl = tid + h * 1024;
        float s1v = s1[ib + rl];
        float thr = -s1v;
        int lo = 0, hi = N_;
        while (lo < hi) { int mid = (lo + hi) >> 1; if (zv[mid] >= thr) hi = mid; else lo = mid + 1; }
        float beta = s1v + m2;
        float wPc, wQc;
        if (beta >= 0.f) { wPc = 1.f;                  wQc = __expf(-0.8f * beta); }
        else             { wPc = __expf(0.8f * beta);  wQc = 1.f; }
        float Sp = Ptot - Ppre[lo];
        float Sq = Qpre[lo];
        float inv = 1.f / (wPc * Sp + wQc * Sq);
        fPArr[ib + rl] = wPc * inv;
        fQArr[ib + rl] = wQc * inv;
        kk[h] = lo;
        sl[h] = atomicAdd(&cnt[lo], 1);
    }
    __syncthreads();

    // --- D: scan of cnt[0..2047] (+ bucket 2048 appended) ---
    int c0 = cnt[2*tid], c1 = cnt[2*tid+1];
    int cv = c0 + c1, ci = cv;
    for (int o = 1; o < 64; o <<= 1) {
        int t = __shfl_up(ci, o);
        if (lane >= o) ci += t;
    }
    if (lane == 63) wsC[wid] = ci;
    __syncthreads();
    if (wid == 0 && lane < 16) {
        int sc = wsC[lane], ic = sc;
        for (int o = 1; o < 16; o <<= 1) { int t = __shfl_up(ic, o); if (lane >= o) ic += t; }
        woC[lane] = ic - sc;
    }
    __syncthreads();
    int inclC = ci + woC[wid];
    int exclC = inclC - cv;
    ps[2*tid] = exclC; ps[2*tid+1] = exclC + c0;
    if (tid == 1023) { ps[2048] = inclC; ps[2049] = inclC + cnt[2048]; }
    __syncthreads();
    posStart[b * 2050 + tid]        = ps[tid];
    posStart[b * 2050 + 1024 + tid] = ps[1024 + tid];
    if (tid < 2) posStart[b * 2050 + 2048 + tid] = ps[2048 + tid];
    // --- E: scatter rows by bucket ---
    #pragma unroll
    for (int h = 0; h < 2; ++h) {
        int rl = tid + h * 1024;
        rowsSorted[ib + ps[kk[h]] + sl[h]] = rl;
    }
}

// K6: fused suffix walk + output emission. Block (b,g) walks chunk g descending,
// emitting out rows bucketed at each position. No big intermediate.
__global__ __launch_bounds__(512) void k_fused(const float* __restrict__ x,
                                               const int* __restrict__ idxArr,
                                               const float* __restrict__ pArr,
                                               const float* __restrict__ qArr,
                                               const float* __restrict__ chP,
                                               const float* __restrict__ chQ,
                                               const float* __restrict__ totQ,
                                               const float* __restrict__ fPArr,
                                               const float* __restrict__ fQArr,
                                               const int* __restrict__ rowsSorted,
                                               const int* __restrict__ posStart,
                                               float* __restrict__ out) {
    int bg = blockIdx.x, b = bg >> 5, g = bg & 31;
    int c = threadIdx.x;
    __shared__ int   srow[L_];
    __shared__ float spv[L_], sqv[L_];
    __shared__ int   sps[66];
    if (c < L_) {
        int j = g * L_ + c;
        srow[c] = idxArr[b * N_ + j];
        spv[c]  = pArr[b * N_ + j];
        sqv[c]  = qArr[b * N_ + j];
    }
    if (c < 66) sps[c] = posStart[b * 2050 + g * L_ + c];
    __syncthreads();
    const float* xb  = x + (size_t)b * N_ * C_;
    const float* fPb = fPArr + (size_t)b * N_;
    const float* fQb = fQArr + (size_t)b * N_;
    const int*   rs  = rowsSorted + (size_t)b * N_;
    float*       ob  = out + (size_t)b * N_ * C_;
    float runP = chP[(size_t)bg * C_ + c];
    float runQ = chQ[(size_t)bg * C_ + c];
    float tq   = totQ[b * C_ + c];
    if (g == G_ - 1) {
        // bucket k == N: no P part, full Q prefix
        for (int u = sps[64]; u < sps[65]; ++u) {
            int r = rs[u];
            ob[(size_t)r * C_ + c] = fPb[r] * runP + fQb[r] * (tq - runQ);
        }
    }
    float xv_next = xb[(size_t)srow[L_ - 1] * C_ + c];
    for (int t = L_ - 1; t >= 0; --t) {
        float xv = xv_next;
        if (t > 0) xv_next = xb[(size_t)srow[t - 1] * C_ + c];
        runP = fmaf(spv[t], xv, runP);
        runQ = fmaf(sqv[t], xv, runQ);
        for (int u = sps[t]; u < sps[t + 1]; ++u) {
            int r = rs[u];
            ob[(size_t)r * C_ + c] = fPb[r] * runP + fQb[r] * (tq - runQ);
        }
    }
}

extern "C" void kernel_launch(void* const* d_in, const int* in_sizes, int n_in,
                              void* d_out, int out_size, void* d_ws, size_t ws_size,
                              hipStream_t stream) {
    const float* x = (const float*)d_in[0];
    const float* w = (const float*)d_in[1];
    const float* a = (const float*)d_in[2];
    float* out = (float*)d_out;
    float* ws  = (float*)d_ws;

    float* v1   = ws + OFF_V1;
    float* v2   = ws + OFF_V2;
    float* s1   = ws + OFF_S1;
    float* s2   = ws + OFF_S2;
    float* zArr = ws + OFF_Z;
    int*   idxA = (int*)(ws + OFF_IDX);
    float* pArr = ws + OFF_P;
    float* qArr = ws + OFF_Q;
    float* chP  = ws + OFF_CHP;
    float* chQ  = ws + OFF_CHQ;
    float* totQ = ws + OFF_TOTQ;
    float* fPA  = ws + OFF_FP;
    float* fQA  = ws + OFF_FQ;
    int*   rows = (int*)(ws + OFF_ROWS);
    int*   pos  = (int*)(ws + OFF_POS);

    k_wa   <<<dim3(C_),      dim3(64),   0, stream>>>(w, a, v1, v2);
    k_s    <<<dim3(4096),    dim3(256),  0, stream>>>(x, v1, v2, s1, s2);
    k_rank <<<dim3(B_ * 32), dim3(256),  0, stream>>>(s2, zArr, idxA, pArr, qArr);
    k_chunk<<<dim3(B_ * G_), dim3(512),  0, stream>>>(x, idxA, pArr, qArr, chP, chQ);
    k_prep <<<dim3(B_),      dim3(1024), 0, stream>>>(s1, zArr, pArr, qArr, chP, chQ, totQ,
                                                      fPA, fQA, rows, pos);
    k_fused<<<dim3(B_ * G_), dim3(512),  0, stream>>>(x, idxA, pArr, qArr, chP, chQ, totQ,
                                                      fPA, fQA, rows, pos, out);
}

// Round 5
// 140.312 us; speedup vs baseline: 1.0854x; 1.0854x over previous
//
#include <hip/hip_runtime.h>
#include <math.h>

#define B_ 8
#define N_ 2048
#define C_ 512
#define G_ 64          // chunks per batch
#define L_ 32          // chunk length = N_/G_

// ---- workspace layout (in floats) ----
static const size_t OFF_V1   = 0;                    // 512
static const size_t OFF_V2   = OFF_V1 + 512;         // 512
static const size_t OFF_S1   = OFF_V2 + 512;         // 16384
static const size_t OFF_S2   = OFF_S1 + 16384;       // 16384
static const size_t OFF_Z    = OFF_S2 + 16384;       // 16384 sorted s2
static const size_t OFF_IDX  = OFF_Z + 16384;        // 16384 perm (int)
static const size_t OFF_P    = OFF_IDX + 16384;      // 16384 p = exp(z-m2)
static const size_t OFF_Q    = OFF_P + 16384;        // 16384 q = exp(0.2(z-m2))
static const size_t OFF_CHP  = OFF_Q + 16384;        // B*G*C = 262144 chunk P sums -> suffix offsets
static const size_t OFF_CHQ  = OFF_CHP + 262144;     // 262144 chunk Q sums -> suffix offsets
static const size_t OFF_TOTQ = OFF_CHQ + 262144;     // 4096 per-(b,c) total Q
static const size_t OFF_EMR  = OFF_TOTQ + 4096;      // 16384 emission row ids (int), bucket order
static const size_t OFF_EMP  = OFF_EMR + 16384;      // 16384 emission fP
static const size_t OFF_EMQ  = OFF_EMP + 16384;      // 16384 emission fQ
static const size_t OFF_POS  = OFF_EMQ + 16384;      // 8*2050 bucket starts (int)
// total ~= 0.69M floats ~= 2.8 MB

// K1: v1 = w @ a1, v2 = w @ a2
__global__ __launch_bounds__(64) void k_wa(const float* __restrict__ w,
                                           const float* __restrict__ a,
                                           float* __restrict__ v1, float* __restrict__ v2) {
    int k = blockIdx.x, lane = threadIdx.x;
    float acc1 = 0.f, acc2 = 0.f;
    for (int c = lane; c < C_; c += 64) {
        float wv = w[k * C_ + c];
        acc1 += wv * a[c];
        acc2 += wv * a[C_ + c];
    }
    for (int o = 32; o > 0; o >>= 1) { acc1 += __shfl_down(acc1, o); acc2 += __shfl_down(acc2, o); }
    if (lane == 0) { v1[k] = acc1; v2[k] = acc2; }
}

// K2: s1[r] = x[r,:]·v1, s2[r] = x[r,:]·v2
__global__ __launch_bounds__(256) void k_s(const float* __restrict__ x,
                                           const float* __restrict__ v1,
                                           const float* __restrict__ v2,
                                           float* __restrict__ s1, float* __restrict__ s2) {
    __shared__ __align__(16) float sv1[C_];
    __shared__ __align__(16) float sv2[C_];
    int tid = threadIdx.x;
    for (int c = tid; c < C_; c += 256) { sv1[c] = v1[c]; sv2[c] = v2[c]; }
    __syncthreads();
    int wave = tid >> 6, lane = tid & 63;
    int r = blockIdx.x * 4 + wave;
    const float4* xr  = reinterpret_cast<const float4*>(x + (size_t)r * C_);
    const float4* w1p = reinterpret_cast<const float4*>(sv1);
    const float4* w2p = reinterpret_cast<const float4*>(sv2);
    float a1 = 0.f, a2 = 0.f;
    #pragma unroll
    for (int half = 0; half < 2; ++half) {
        int c4 = lane + half * 64;
        float4 xv = xr[c4], w1 = w1p[c4], w2 = w2p[c4];
        a1 += xv.x*w1.x + xv.y*w1.y + xv.z*w1.z + xv.w*w1.w;
        a2 += xv.x*w2.x + xv.y*w2.y + xv.z*w2.z + xv.w*w2.w;
    }
    for (int o = 32; o > 0; o >>= 1) { a1 += __shfl_down(a1, o); a2 += __shfl_down(a2, o); }
    if (lane == 0) { s1[r] = a1; s2[r] = a2; }
}

// K3: rank-by-counting sort of s2 -> z (sorted), idx (perm), p, q
__global__ __launch_bounds__(256) void k_rank(const float* __restrict__ s2,
                                              float* __restrict__ z, int* __restrict__ idxArr,
                                              float* __restrict__ pArr, float* __restrict__ qArr) {
    __shared__ float sval[N_];
    __shared__ float sred[256];
    __shared__ int   srnk[256];
    int blk = blockIdx.x;
    int b = blk >> 5, grp = blk & 31;
    int tid = threadIdx.x;
    int le = tid & 63, qtr = tid >> 6;
    for (int i = tid; i < N_; i += 256) sval[i] = s2[(size_t)b * N_ + i];
    __syncthreads();
    int e = grp * 64 + le;
    float val = sval[e];
    int base = qtr * 512;
    int rank = 0;
    float mx = -3.4e38f;
    #pragma unroll 8
    for (int i = 0; i < 512; ++i) {
        int t = base + i;
        float v = sval[t];
        mx = fmaxf(mx, v);
        rank += (v < val) || (v == val && t < e);
    }
    srnk[tid] = rank;
    sred[tid] = mx;
    __syncthreads();
    for (int o = 128; o > 0; o >>= 1) {
        if (tid < o) sred[tid] = fmaxf(sred[tid], sred[tid + o]);
        __syncthreads();
    }
    float m2 = sred[0];
    if (qtr == 0) {
        int rk = srnk[le] + srnk[le + 64] + srnk[le + 128] + srnk[le + 192];
        float d = val - m2;
        size_t pos = (size_t)b * N_ + rk;
        z[pos]      = val;
        idxArr[pos] = e;
        pArr[pos]   = __expf(d);
        qArr[pos]   = __expf(0.2f * d);
    }
}

// K4: per-chunk vector sums chP/chQ[b,g,c] — fully unrolled, loads pipelined
__global__ __launch_bounds__(512) void k_chunk(const float* __restrict__ x,
                                               const int* __restrict__ idxArr,
                                               const float* __restrict__ pArr,
                                               const float* __restrict__ qArr,
                                               float* __restrict__ chP, float* __restrict__ chQ) {
    int bg = blockIdx.x, b = bg >> 6, g = bg & 63;
    int c = threadIdx.x;
    __shared__ int   srow[L_];
    __shared__ float spv[L_], sqv[L_];
    if (c < L_) {
        int j = g * L_ + c;
        srow[c] = idxArr[b * N_ + j];
        spv[c]  = pArr[b * N_ + j];
        sqv[c]  = qArr[b * N_ + j];
    }
    __syncthreads();
    const float* xb = x + (size_t)b * N_ * C_;
    float xr_[L_];
    #pragma unroll
    for (int t = 0; t < L_; ++t) xr_[t] = xb[(size_t)srow[t] * C_ + c];
    float accP = 0.f, accQ = 0.f;
    #pragma unroll
    for (int t = 0; t < L_; ++t) {
        accP = fmaf(spv[t], xr_[t], accP);
        accQ = fmaf(sqv[t], xr_[t], accQ);
    }
    chP[(size_t)bg * C_ + c] = accP;
    chQ[(size_t)bg * C_ + c] = accQ;
}

// K5: per-batch prep (one block per batch, 1024 threads):
//  A) scalar exclusive prefixes of p,q (LDS only)
//  B) chunk sums -> exclusive suffix offsets in place + totQ
//  C) per output row: binary search split k, factors fP/fQ, bucket count
//  D) scan bucket counts -> posStart
//  E) scatter emission records (row, fP, fQ) in bucket order
__global__ __launch_bounds__(1024) void k_prep(const float* __restrict__ s1,
                                               const float* __restrict__ z,
                                               const float* __restrict__ pArr,
                                               const float* __restrict__ qArr,
                                               float* __restrict__ chP,
                                               float* __restrict__ chQ,
                                               float* __restrict__ totQ,
                                               int* __restrict__ emRow,
                                               float* __restrict__ emFP,
                                               float* __restrict__ emFQ,
                                               int* __restrict__ posStart) {
    __shared__ float Ppre[2049], Qpre[2049];
    __shared__ float zv[N_];
    __shared__ int   cnt[2049];
    __shared__ int   ps[2050];
    __shared__ float wsP[16], wsQ[16], woP[16], woQ[16];
    __shared__ int   wsC[16], woC[16];
    int b = blockIdx.x, tid = threadIdx.x, lane = tid & 63, wid = tid >> 6;
    size_t ib = (size_t)b * N_;

    for (int i = tid; i < 2049; i += 1024) cnt[i] = 0;
    zv[2*tid]   = z[ib + 2*tid];
    zv[2*tid+1] = z[ib + 2*tid+1];

    // --- A: scalar scans of p and q ---
    float p0 = pArr[ib + 2*tid], p1 = pArr[ib + 2*tid+1];
    float q0 = qArr[ib + 2*tid], q1 = qArr[ib + 2*tid+1];
    float pv = p0 + p1, qv = q0 + q1;
    float pi = pv, qi = qv;
    for (int o = 1; o < 64; o <<= 1) {
        float tp = __shfl_up(pi, o), tq2 = __shfl_up(qi, o);
        if (lane >= o) { pi += tp; qi += tq2; }
    }
    if (lane == 63) { wsP[wid] = pi; wsQ[wid] = qi; }
    __syncthreads();
    if (wid == 0 && lane < 16) {
        float sp = wsP[lane], sq = wsQ[lane];
        float ip = sp, iq = sq;
        for (int o = 1; o < 16; o <<= 1) {
            float tp = __shfl_up(ip, o), tq2 = __shfl_up(iq, o);
            if (lane >= o) { ip += tp; iq += tq2; }
        }
        woP[lane] = ip - sp; woQ[lane] = iq - sq;
    }
    // --- B: chunk suffix offsets (independent of A's tail) ---
    {
        int c = tid & 511, sel = tid >> 9;
        float* arr = sel ? chQ : chP;
        float v[G_];
        #pragma unroll
        for (int g = 0; g < G_; ++g)
            v[g] = arr[((size_t)(b * G_ + g)) * C_ + c];
        float run = 0.f;
        #pragma unroll
        for (int g = G_ - 1; g >= 0; --g) {
            float t = v[g];
            arr[((size_t)(b * G_ + g)) * C_ + c] = run;
            run += t;
        }
        if (sel) totQ[b * C_ + c] = run;
    }
    __syncthreads();
    float inclP = pi + woP[wid], inclQ = qi + woQ[wid];
    float exclP = inclP - pv,    exclQ = inclQ - qv;
    Ppre[2*tid]   = exclP;  Ppre[2*tid+1] = exclP + p0;
    Qpre[2*tid]   = exclQ;  Qpre[2*tid+1] = exclQ + q0;
    if (tid == 1023) { Ppre[2048] = inclP; Qpre[2048] = inclQ; }
    __syncthreads();

    // --- C: per-row split + factors + bucket count ---
    float m2   = zv[N_ - 1];
    float Ptot = Ppre[2048];
    int   kk[2], sl[2];
    float fPv[2], fQv[2];
    #pragma unroll
    for (int h = 0; h < 2; ++h) {
        int rl = tid + h * 1024;
        float s1v = s1[ib + rl];
        float thr = -s1v;
        int lo = 0, hi = N_;
        while (lo < hi) { int mid = (lo + hi) >> 1; if (zv[mid] >= thr) hi = mid; else lo = mid + 1; }
        float beta = s1v + m2;
        float wPc, wQc;
        if (beta >= 0.f) { wPc = 1.f;                  wQc = __expf(-0.8f * beta); }
        else             { wPc = __expf(0.8f * beta);  wQc = 1.f; }
        float Sp = Ptot - Ppre[lo];
        float Sq = Qpre[lo];
        float inv = 1.f / (wPc * Sp + wQc * Sq);
        fPv[h] = wPc * inv;
        fQv[h] = wQc * inv;
        kk[h] = lo;
        sl[h] = atomicAdd(&cnt[lo], 1);
    }
    __syncthreads();

    // --- D: scan of cnt[0..2047] (+ bucket 2048 appended) ---
    int c0 = cnt[2*tid], c1 = cnt[2*tid+1];
    int cv = c0 + c1, ci = cv;
    for (int o = 1; o < 64; o <<= 1) {
        int t = __shfl_up(ci, o);
        if (lane >= o) ci += t;
    }
    if (lane == 63) wsC[wid] = ci;
    __syncthreads();
    if (wid == 0 && lane < 16) {
        int sc = wsC[lane], ic = sc;
        for (int o = 1; o < 16; o <<= 1) { int t = __shfl_up(ic, o); if (lane >= o) ic += t; }
        woC[lane] = ic - sc;
    }
    __syncthreads();
    int inclC = ci + woC[wid];
    int exclC = inclC - cv;
    ps[2*tid] = exclC; ps[2*tid+1] = exclC + c0;
    if (tid == 1023) { ps[2048] = inclC; ps[2049] = inclC + cnt[2048]; }
    __syncthreads();
    posStart[b * 2050 + tid]        = ps[tid];
    posStart[b * 2050 + 1024 + tid] = ps[1024 + tid];
    if (tid < 2) posStart[b * 2050 + 2048 + tid] = ps[2048 + tid];
    // --- E: scatter emission records in bucket order ---
    #pragma unroll
    for (int h = 0; h < 2; ++h) {
        int rl = tid + h * 1024;
        int u  = ps[kk[h]] + sl[h];
        emRow[ib + u] = rl;
        emFP [ib + u] = fPv[h];
        emFQ [ib + u] = fQv[h];
    }
}

// K6: fused suffix walk + output emission. Block (b,g) walks chunk g descending.
// Rows register-blocked; emission records preloaded to LDS.
__global__ __launch_bounds__(512) void k_fused(const float* __restrict__ x,
                                               const int* __restrict__ idxArr,
                                               const float* __restrict__ pArr,
                                               const float* __restrict__ qArr,
                                               const float* __restrict__ chP,
                                               const float* __restrict__ chQ,
                                               const float* __restrict__ totQ,
                                               const int* __restrict__ emRow,
                                               const float* __restrict__ emFP,
                                               const float* __restrict__ emFQ,
                                               const int* __restrict__ posStart,
                                               float* __restrict__ out) {
    int bg = blockIdx.x, b = bg >> 6, g = bg & 63;
    int c = threadIdx.x;
    __shared__ int   srow[L_];
    __shared__ float spv[L_], sqv[L_];
    __shared__ int   sps[L_ + 2];
    __shared__ int   semRow[N_];
    __shared__ float semFP[N_], semFQ[N_];
    if (c < L_) {
        int j = g * L_ + c;
        srow[c] = idxArr[b * N_ + j];
        spv[c]  = pArr[b * N_ + j];
        sqv[c]  = qArr[b * N_ + j];
    }
    if (c < L_ + 2) sps[c] = posStart[b * 2050 + g * L_ + c];
    __syncthreads();
    int uStart = sps[0];
    int uEnd   = (g == G_ - 1) ? sps[L_ + 1] : sps[L_];
    size_t ib = (size_t)b * N_;
    for (int u = uStart + c; u < uEnd; u += 512) {
        int e = u - uStart;
        semRow[e] = emRow[ib + u];
        semFP[e]  = emFP [ib + u];
        semFQ[e]  = emFQ [ib + u];
    }
    __syncthreads();
    const float* xb = x + (size_t)b * N_ * C_;
    float*       ob = out + (size_t)b * N_ * C_;
    float xr_[L_];
    #pragma unroll
    for (int t = 0; t < L_; ++t) xr_[t] = xb[(size_t)srow[t] * C_ + c];
    float runP = chP[(size_t)bg * C_ + c];
    float runQ = chQ[(size_t)bg * C_ + c];
    float tq   = totQ[b * C_ + c];
    if (g == G_ - 1) {
        // bucket k == N: no P part, full Q prefix
        for (int u = sps[L_]; u < sps[L_ + 1]; ++u) {
            int e = u - uStart;
            ob[(size_t)semRow[e] * C_ + c] = semFP[e] * runP + semFQ[e] * (tq - runQ);
        }
    }
    #pragma unroll
    for (int t = L_ - 1; t >= 0; --t) {
        runP = fmaf(spv[t], xr_[t], runP);
        runQ = fmaf(sqv[t], xr_[t], runQ);
        for (int u = sps[t]; u < sps[t + 1]; ++u) {
            int e = u - uStart;
            ob[(size_t)semRow[e] * C_ + c] = semFP[e] * runP + semFQ[e] * (tq - runQ);
        }
    }
}

extern "C" void kernel_launch(void* const* d_in, const int* in_sizes, int n_in,
                              void* d_out, int out_size, void* d_ws, size_t ws_size,
                              hipStream_t stream) {
    const float* x = (const float*)d_in[0];
    const float* w = (const float*)d_in[1];
    const float* a = (const float*)d_in[2];
    float* out = (float*)d_out;
    float* ws  = (float*)d_ws;

    float* v1   = ws + OFF_V1;
    float* v2   = ws + OFF_V2;
    float* s1   = ws + OFF_S1;
    float* s2   = ws + OFF_S2;
    float* zArr = ws + OFF_Z;
    int*   idxA = (int*)(ws + OFF_IDX);
    float* pArr = ws + OFF_P;
    float* qArr = ws + OFF_Q;
    float* chP  = ws + OFF_CHP;
    float* chQ  = ws + OFF_CHQ;
    float* totQ = ws + OFF_TOTQ;
    int*   emR  = (int*)(ws + OFF_EMR);
    float* emP  = ws + OFF_EMP;
    float* emQ  = ws + OFF_EMQ;
    int*   pos  = (int*)(ws + OFF_POS);

    k_wa   <<<dim3(C_),      dim3(64),   0, stream>>>(w, a, v1, v2);
    k_s    <<<dim3(4096),    dim3(256),  0, stream>>>(x, v1, v2, s1, s2);
    k_rank <<<dim3(B_ * 32), dim3(256),  0, stream>>>(s2, zArr, idxA, pArr, qArr);
    k_chunk<<<dim3(B_ * G_), dim3(512),  0, stream>>>(x, idxA, pArr, qArr, chP, chQ);
    k_prep <<<dim3(B_),      dim3(1024), 0, stream>>>(s1, zArr, pArr, qArr, chP, chQ, totQ,
                                                      emR, emP, emQ, pos);
    k_fused<<<dim3(B_ * G_), dim3(512),  0, stream>>>(x, idxA, pArr, qArr, chP, chQ, totQ,
                                                      emR, emP, emQ, pos, out);
}